// Round 1
// baseline (166.723 us; speedup 1.0000x reference)
//
#include <hip/hip_runtime.h>
#include <math.h>

#define NAGENT 4096
#define TOPK 32
#define FAGB 8    // agents per block in fused kernel (8 waves x 1 agent)
#define CANDCAP 2048

// ---------------------------------------------------------------------------
// Kernel 1: exact top-32 nearest neighbors. VERBATIM from R12 (PASSED).
// ---------------------------------------------------------------------------
__global__ __launch_bounds__(256) void topk_kernel(
    const float* __restrict__ states, int* __restrict__ idx_out)
{
    const int i = blockIdx.x;
    const int t = threadIdx.x;
    const int lane = t & 63;
    __shared__ unsigned int hist[1024];
    __shared__ unsigned int wsum[4];
    __shared__ unsigned long long cand[CANDCAP];
    __shared__ int ccount;
    __shared__ unsigned int cutB;

    #pragma unroll
    for (int u = 0; u < 4; ++u) hist[t + u * 256] = 0u;
    if (t == 0) ccount = 0;

    const float4 si = ((const float4*)states)[i];
    __syncthreads();

    unsigned int mybits[16];
    #pragma unroll
    for (int u = 0; u < 16; ++u) {
        int j = t + u * 256;
        float4 sj = ((const float4*)states)[j];
        float dx = __fsub_rn(si.x, sj.x);
        float dy = __fsub_rn(si.y, sj.y);
        float s  = __fadd_rn(__fadd_rn(__fmul_rn(dx, dx), __fmul_rn(dy, dy)), 1e-4f);
        float dv = sqrtf(s);
        mybits[u] = __float_as_uint(dv);
        unsigned int bin = (unsigned int)(dv * 256.0f);
        if (bin > 1023u) bin = 1023u;
        atomicAdd(&hist[bin], 1u);
    }
    __syncthreads();

    unsigned int h0 = hist[t * 4 + 0], h1 = hist[t * 4 + 1];
    unsigned int h2 = hist[t * 4 + 2], h3 = hist[t * 4 + 3];
    unsigned int v = h0 + h1 + h2 + h3;
    unsigned int inc = v;
    #pragma unroll
    for (int off = 1; off < 64; off <<= 1) {
        unsigned int u = __shfl_up(inc, off, 64);
        if (lane >= off) inc += u;
    }
    if (lane == 63) wsum[t >> 6] = inc;
    __syncthreads();
    unsigned int woff = 0;
    for (int w = 0; w < (t >> 6); ++w) woff += wsum[w];
    unsigned int incl = inc + woff;
    unsigned int exc  = incl - v;
    if (exc < TOPK && incl >= TOPK) {
        unsigned int cum = exc;
        unsigned int hh[4] = {h0, h1, h2, h3};
        int b = t * 4 + 3;
        #pragma unroll
        for (int q = 0; q < 4; ++q) {
            cum += hh[q];
            if (cum >= TOPK) { b = t * 4 + q; break; }
        }
        cutB = (unsigned int)b;
    }
    __syncthreads();

    const unsigned int B = cutB;
    #pragma unroll
    for (int u = 0; u < 16; ++u) {
        float dv = __uint_as_float(mybits[u]);
        unsigned int bin = (unsigned int)(dv * 256.0f);
        if (bin > 1023u) bin = 1023u;
        if (bin <= B) {
            int pos = atomicAdd(&ccount, 1);
            if (pos < CANDCAP)
                cand[pos] = ((unsigned long long)mybits[u] << 32)
                          | (unsigned int)(t + u * 256);
        }
    }
    __syncthreads();

    const int C = (ccount < CANDCAP) ? ccount : CANDCAP;
    for (int q = t; q < C; q += 256) {
        unsigned long long key = cand[q];
        int rank = 0;
        for (int r = 0; r < C; ++r) rank += (cand[r] < key) ? 1 : 0;
        if (rank < TOPK) idx_out[i * TOPK + rank] = (int)(key & 0xffffffffu);
    }
}

// ---------------------------------------------------------------------------
// Kernel 2 (fused) R14: 512-thread / 8-wave blocks, 1 agent per wave, no
// rounds. h1 split into p-halves (recomputed per half, W2 LDS re-read x2)
// so LDS = 80000 B -> still 2 blocks/CU but 16 waves/CU = 4 waves/SIMD
// (was 2/SIMD). Per-accumulator c-order, h1 expressions, argmax key packing
// and dense math bitwise-identical to R13. Dense phase is wave-private
// (z-pool aliases own h1 region) -> single barrier in the whole kernel.
// ---------------------------------------------------------------------------
__global__ __launch_bounds__(512, 4) void fused_kernel(
    const float* __restrict__ states, const float* __restrict__ goals,
    const float* __restrict__ W1,  const float* __restrict__ b1,
    const float* __restrict__ W2,  const float* __restrict__ b2,
    const float* __restrict__ Wd1, const float* __restrict__ bd1,
    const float* __restrict__ Wd2, const float* __restrict__ bd2,
    const float* __restrict__ Wd3, const float* __restrict__ bd3,
    const float* __restrict__ Wd4, const float* __restrict__ bd4,
    const int* __restrict__ idx_in, float* __restrict__ out)
{
    const int t = threadIdx.x;
    const int a = t >> 6;               // wave id == local agent id (0..7)
    const int l = t & 63;
    const int base = blockIdx.x * FAGB;
    const int i = base + a;

    __shared__ __attribute__((aligned(16))) float w2a[64 * 68];    // 17.0 KB
    __shared__ __attribute__((aligned(16))) float w2b[64 * 68];    // 17.0 KB
    __shared__ __attribute__((aligned(16))) float w1s[320];
    __shared__ __attribute__((aligned(16))) float b1s[64];
    __shared__ __attribute__((aligned(16))) float b2s[128];
    __shared__ __attribute__((aligned(16))) float flat[8][160];    // 5.0 KB
    __shared__ __attribute__((aligned(16))) float maskv[8][32];    // 1.0 KB
    __shared__ __attribute__((aligned(16))) float featb[8][132];   // 4.1 KB
    __shared__ __attribute__((aligned(16))) float h1p[8][1024];    // 32 KB: h1 half / z-pool
    // total: 80000 B -> 2 blocks/CU (160 KB), 16 waves/CU

    // ---- gather FIRST: the dependent idx->states chain overlaps W2 staging
    if (l < 32) {
        int j = idx_in[i * TOPK + l];
        float4 sj  = ((const float4*)states)[j];
        float4 siv = ((const float4*)states)[i];
        float d0 = siv.x - sj.x;
        float d1 = siv.y - sj.y;
        float d2 = siv.z - sj.z;
        float d3 = siv.w - sj.w;
        flat[a][l * 5 + 0] = d0;
        flat[a][l * 5 + 1] = d1;
        flat[a][l * 5 + 2] = d2;
        flat[a][l * 5 + 3] = d3;
        flat[a][l * 5 + 4] = (j == i) ? 1.0f : 0.0f;
        float dist = sqrtf(__fadd_rn(__fmul_rn(d0, d0), __fmul_rn(d1, d1)));
        maskv[a][l] = (dist < 1.0f) ? 1.0f : 0.0f;
    } else if (l < 36) {
        int f = l - 32;
        float4 siv = ((const float4*)states)[i];
        float2 gi  = ((const float2*)goals)[i];
        float v = (f == 0) ? (siv.x - gi.x)
                : (f == 1) ? (siv.y - gi.y)
                : (f == 2) ? siv.z : siv.w;
        featb[a][128 + f] = v;
    }

    // ---- stage W2 split + small weights (512 threads, same dst formula as R13)
    #pragma unroll
    for (int u = 0; u < 16; ++u) {
        int e = t + u * 512;
        int o = e >> 6, c = e & 63;
        float v = W2[e];
        int dst = c * 68 + ((o >> 3) << 2) + (o & 3);
        if (o & 4) w2b[dst] = v; else w2a[dst] = v;
    }
    if (t < 320) w1s[t] = W1[t];
    if (t < 64)  b1s[t] = b1[t];
    if (t < 128) b2s[t] = b2[t];
    __syncthreads();   // the only barrier

    // ---- h2 lane tile: o in [ow*8, +8), p in [pq*16 + ph*4, +4)
    const int ow = l & 15;
    const int ph = l >> 4;

    float bb[8];
    #pragma unroll
    for (int k = 0; k < 8; ++k) bb[k] = b2s[ow * 8 + k];

    unsigned long long rbest[8];
    #pragma unroll
    for (int k = 0; k < 8; ++k) rbest[k] = 0ull;

    #pragma unroll
    for (int pq = 0; pq < 2; ++pq) {
        // ---- h1 half: c in [0,64), pp in [0,16)  (wave-private, in-order DS)
        #pragma unroll
        for (int u = 0; u < 16; ++u) {
            int e = u * 64 + l;            // 0..1023
            int o1 = e >> 4, pp = e & 15;
            float acc = b1s[o1];
            #pragma unroll
            for (int f = 0; f < 5; ++f)
                acc += w1s[o1 * 5 + f] * flat[a][f * 32 + pq * 16 + pp];
            h1p[a][e] = fmaxf(acc, 0.0f);  // e == o1*16 + pp
        }

        float4 mv4 = *(const float4*)&maskv[a][pq * 16 + ph * 4];
        float mv[4] = {mv4.x, mv4.y, mv4.z, mv4.w};

        float acc[8][4];
        #pragma unroll
        for (int k = 0; k < 8; ++k)
            #pragma unroll
            for (int q = 0; q < 4; ++q) acc[k][q] = 0.0f;

        for (int c4 = 0; c4 < 16; ++c4) {
            float4 wAv[4], wBv[4], hv[4];
            #pragma unroll
            for (int cc = 0; cc < 4; ++cc) {
                int c = c4 * 4 + cc;
                wAv[cc] = *(const float4*)&w2a[c * 68 + ow * 4];
                wBv[cc] = *(const float4*)&w2b[c * 68 + ow * 4];
                hv[cc]  = *(const float4*)&h1p[a][c * 16 + ph * 4];
            }
            #pragma unroll
            for (int cc = 0; cc < 4; ++cc) {
                float wv[8] = {wAv[cc].x, wAv[cc].y, wAv[cc].z, wAv[cc].w,
                               wBv[cc].x, wBv[cc].y, wBv[cc].z, wBv[cc].w};
                float hq[4] = {hv[cc].x, hv[cc].y, hv[cc].z, hv[cc].w};
                #pragma unroll
                for (int k = 0; k < 8; ++k)
                    #pragma unroll
                    for (int q = 0; q < 4; ++q)
                        acc[k][q] += wv[k] * hq[q];   // c ascending: same order as R13
            }
        }

        // ---- bias + relu + mask + partial argmax (running best across halves)
        #pragma unroll
        for (int k = 0; k < 8; ++k) {
            unsigned long long best = rbest[k];
            #pragma unroll
            for (int q = 0; q < 4; ++q) {
                float val = fmaxf(acc[k][q] + bb[k], 0.0f) * mv[q];
                int p = pq * 16 + ph * 4 + q;
                unsigned long long key =
                    ((unsigned long long)__float_as_uint(val) << 32)
                    | (unsigned int)(31 - p);
                if (key > best) best = key;
            }
            rbest[k] = best;
        }
    }

    // ---- cross-lane reduce over ph groups (covers all 32 p) + write feat
    #pragma unroll
    for (int k = 0; k < 8; ++k) {
        unsigned long long best = rbest[k];
        unsigned long long o1 = __shfl_xor(best, 16, 64); if (o1 > best) best = o1;
        unsigned long long o2 = __shfl_xor(best, 32, 64); if (o2 > best) best = o2;
        if (ph == 0) {
            int pbest = 31 - (int)(best & 63ull);
            featb[a][ow * 8 + k] = (float)pbest;
        }
    }

    // ---- dense phase: fully wave-private (z-pool aliases own h1 region,
    //      which this wave is done with). No barrier needed.
    float* z1s = &h1p[a][0];      // 64
    float* z2s = z1s + 64;        // 128
    float* z3s = z1s + 192;       // 64
    float* kvs = z1s + 256;       // 4

    {
        float a0 = bd1[l];
        for (int k = 0; k < 33; ++k) {
            float4 wv = *(const float4*)&Wd1[l * 132 + 4 * k];
            float4 f0 = *(const float4*)&featb[a][4 * k];
            a0 += wv.x * f0.x; a0 += wv.y * f0.y; a0 += wv.z * f0.z; a0 += wv.w * f0.w;
        }
        z1s[l] = fmaxf(a0, 0.0f);
    }

    {
        float accA = bd2[l];
        float accB = bd2[l + 64];
        for (int k = 0; k < 16; ++k) {
            float4 wa = *(const float4*)&Wd2[l * 64 + 4 * k];
            float4 wb = *(const float4*)&Wd2[(l + 64) * 64 + 4 * k];
            float4 f0 = *(const float4*)&z1s[4 * k];
            accA += wa.x * f0.x; accA += wa.y * f0.y;
            accA += wa.z * f0.z; accA += wa.w * f0.w;
            accB += wb.x * f0.x; accB += wb.y * f0.y;
            accB += wb.z * f0.z; accB += wb.w * f0.w;
        }
        z2s[l]      = fmaxf(accA, 0.0f);
        z2s[l + 64] = fmaxf(accB, 0.0f);
    }

    {
        float a0 = bd3[l];
        for (int k = 0; k < 32; ++k) {
            float4 wv = *(const float4*)&Wd3[l * 128 + 4 * k];
            float4 f0 = *(const float4*)&z2s[4 * k];
            a0 += wv.x * f0.x; a0 += wv.y * f0.y; a0 += wv.z * f0.z; a0 += wv.w * f0.w;
        }
        z3s[l] = fmaxf(a0, 0.0f);
    }

    if (l < 4) {
        float acc = bd4[l];
        for (int c = 0; c < 64; ++c) acc += Wd4[l * 64 + c] * z3s[c];
        kvs[l] = 2.0f / (1.0f + expf(-acc)) + 0.2f;
    }
    if (l < 2) {
        float ka = kvs[2 * l + 0];
        float kb = kvs[2 * l + 1];
        float rel = featb[a][128 + l];
        float vel = featb[a][130 + l];
        out[i * 2 + l] = -(ka * rel + kb * vel);
    }
}

extern "C" void kernel_launch(void* const* d_in, const int* in_sizes, int n_in,
                              void* d_out, int out_size, void* d_ws, size_t ws_size,
                              hipStream_t stream)
{
    const float* states = (const float*)d_in[0];
    const float* goals  = (const float*)d_in[1];
    const float* W1  = (const float*)d_in[2];
    const float* b1  = (const float*)d_in[3];
    const float* W2  = (const float*)d_in[4];
    const float* b2  = (const float*)d_in[5];
    const float* Wd1 = (const float*)d_in[6];
    const float* bd1 = (const float*)d_in[7];
    const float* Wd2 = (const float*)d_in[8];
    const float* bd2 = (const float*)d_in[9];
    const float* Wd3 = (const float*)d_in[10];
    const float* bd3 = (const float*)d_in[11];
    const float* Wd4 = (const float*)d_in[12];
    const float* bd4 = (const float*)d_in[13];

    int*   idx = (int*)d_ws;   // 512 KB
    float* out = (float*)d_out;

    topk_kernel<<<NAGENT, 256, 0, stream>>>(states, idx);
    fused_kernel<<<NAGENT / FAGB, 512, 0, stream>>>(states, goals, W1, b1, W2, b2,
                                                    Wd1, bd1, Wd2, bd2, Wd3, bd3,
                                                    Wd4, bd4, idx, out);
}

// Round 2
// 158.917 us; speedup vs baseline: 1.0491x; 1.0491x over previous
//
#include <hip/hip_runtime.h>
#include <math.h>

#define NAGENT 4096
#define TOPK 32
#define FAGB 8    // agents per block in fused kernel (8 waves x 1 agent)
#define CANDCAP 2048

// ---------------------------------------------------------------------------
// Kernel 1: exact top-32 nearest neighbors. VERBATIM from R12 (PASSED).
// ---------------------------------------------------------------------------
__global__ __launch_bounds__(256) void topk_kernel(
    const float* __restrict__ states, int* __restrict__ idx_out)
{
    const int i = blockIdx.x;
    const int t = threadIdx.x;
    const int lane = t & 63;
    __shared__ unsigned int hist[1024];
    __shared__ unsigned int wsum[4];
    __shared__ unsigned long long cand[CANDCAP];
    __shared__ int ccount;
    __shared__ unsigned int cutB;

    #pragma unroll
    for (int u = 0; u < 4; ++u) hist[t + u * 256] = 0u;
    if (t == 0) ccount = 0;

    const float4 si = ((const float4*)states)[i];
    __syncthreads();

    unsigned int mybits[16];
    #pragma unroll
    for (int u = 0; u < 16; ++u) {
        int j = t + u * 256;
        float4 sj = ((const float4*)states)[j];
        float dx = __fsub_rn(si.x, sj.x);
        float dy = __fsub_rn(si.y, sj.y);
        float s  = __fadd_rn(__fadd_rn(__fmul_rn(dx, dx), __fmul_rn(dy, dy)), 1e-4f);
        float dv = sqrtf(s);
        mybits[u] = __float_as_uint(dv);
        unsigned int bin = (unsigned int)(dv * 256.0f);
        if (bin > 1023u) bin = 1023u;
        atomicAdd(&hist[bin], 1u);
    }
    __syncthreads();

    unsigned int h0 = hist[t * 4 + 0], h1 = hist[t * 4 + 1];
    unsigned int h2 = hist[t * 4 + 2], h3 = hist[t * 4 + 3];
    unsigned int v = h0 + h1 + h2 + h3;
    unsigned int inc = v;
    #pragma unroll
    for (int off = 1; off < 64; off <<= 1) {
        unsigned int u = __shfl_up(inc, off, 64);
        if (lane >= off) inc += u;
    }
    if (lane == 63) wsum[t >> 6] = inc;
    __syncthreads();
    unsigned int woff = 0;
    for (int w = 0; w < (t >> 6); ++w) woff += wsum[w];
    unsigned int incl = inc + woff;
    unsigned int exc  = incl - v;
    if (exc < TOPK && incl >= TOPK) {
        unsigned int cum = exc;
        unsigned int hh[4] = {h0, h1, h2, h3};
        int b = t * 4 + 3;
        #pragma unroll
        for (int q = 0; q < 4; ++q) {
            cum += hh[q];
            if (cum >= TOPK) { b = t * 4 + q; break; }
        }
        cutB = (unsigned int)b;
    }
    __syncthreads();

    const unsigned int B = cutB;
    #pragma unroll
    for (int u = 0; u < 16; ++u) {
        float dv = __uint_as_float(mybits[u]);
        unsigned int bin = (unsigned int)(dv * 256.0f);
        if (bin > 1023u) bin = 1023u;
        if (bin <= B) {
            int pos = atomicAdd(&ccount, 1);
            if (pos < CANDCAP)
                cand[pos] = ((unsigned long long)mybits[u] << 32)
                          | (unsigned int)(t + u * 256);
        }
    }
    __syncthreads();

    const int C = (ccount < CANDCAP) ? ccount : CANDCAP;
    for (int q = t; q < C; q += 256) {
        unsigned long long key = cand[q];
        int rank = 0;
        for (int r = 0; r < C; ++r) rank += (cand[r] < key) ? 1 : 0;
        if (rank < TOPK) idx_out[i * TOPK + rank] = (int)(key & 0xffffffffu);
    }
}

// ---------------------------------------------------------------------------
// Kernel 2 (fused) R15: identical structure to R14 (8 waves x 1 agent,
// h1 p-halves, 80 KB LDS, single barrier). ONE change:
// __launch_bounds__(512, 2) instead of (512, 4). R14's "4" was interpreted
// as 4 blocks/CU -> 8 waves/SIMD -> 64-VGPR cap -> massive scratch spills
// (FETCH 17.6 MB, WRITE 33.8 MB, VALUBusy 33%). "2" matches the LDS limit
// (80 KB -> 2 blocks/CU) and restores the 128-VGPR budget.
// ---------------------------------------------------------------------------
__global__ __launch_bounds__(512, 2) void fused_kernel(
    const float* __restrict__ states, const float* __restrict__ goals,
    const float* __restrict__ W1,  const float* __restrict__ b1,
    const float* __restrict__ W2,  const float* __restrict__ b2,
    const float* __restrict__ Wd1, const float* __restrict__ bd1,
    const float* __restrict__ Wd2, const float* __restrict__ bd2,
    const float* __restrict__ Wd3, const float* __restrict__ bd3,
    const float* __restrict__ Wd4, const float* __restrict__ bd4,
    const int* __restrict__ idx_in, float* __restrict__ out)
{
    const int t = threadIdx.x;
    const int a = t >> 6;               // wave id == local agent id (0..7)
    const int l = t & 63;
    const int base = blockIdx.x * FAGB;
    const int i = base + a;

    __shared__ __attribute__((aligned(16))) float w2a[64 * 68];    // 17.0 KB
    __shared__ __attribute__((aligned(16))) float w2b[64 * 68];    // 17.0 KB
    __shared__ __attribute__((aligned(16))) float w1s[320];
    __shared__ __attribute__((aligned(16))) float b1s[64];
    __shared__ __attribute__((aligned(16))) float b2s[128];
    __shared__ __attribute__((aligned(16))) float flat[8][160];    // 5.0 KB
    __shared__ __attribute__((aligned(16))) float maskv[8][32];    // 1.0 KB
    __shared__ __attribute__((aligned(16))) float featb[8][132];   // 4.1 KB
    __shared__ __attribute__((aligned(16))) float h1p[8][1024];    // 32 KB: h1 half / z-pool
    // total: 80000 B -> 2 blocks/CU (160 KB), 16 waves/CU

    // ---- gather FIRST: the dependent idx->states chain overlaps W2 staging
    if (l < 32) {
        int j = idx_in[i * TOPK + l];
        float4 sj  = ((const float4*)states)[j];
        float4 siv = ((const float4*)states)[i];
        float d0 = siv.x - sj.x;
        float d1 = siv.y - sj.y;
        float d2 = siv.z - sj.z;
        float d3 = siv.w - sj.w;
        flat[a][l * 5 + 0] = d0;
        flat[a][l * 5 + 1] = d1;
        flat[a][l * 5 + 2] = d2;
        flat[a][l * 5 + 3] = d3;
        flat[a][l * 5 + 4] = (j == i) ? 1.0f : 0.0f;
        float dist = sqrtf(__fadd_rn(__fmul_rn(d0, d0), __fmul_rn(d1, d1)));
        maskv[a][l] = (dist < 1.0f) ? 1.0f : 0.0f;
    } else if (l < 36) {
        int f = l - 32;
        float4 siv = ((const float4*)states)[i];
        float2 gi  = ((const float2*)goals)[i];
        float v = (f == 0) ? (siv.x - gi.x)
                : (f == 1) ? (siv.y - gi.y)
                : (f == 2) ? siv.z : siv.w;
        featb[a][128 + f] = v;
    }

    // ---- stage W2 split + small weights (512 threads, same dst formula as R13)
    #pragma unroll
    for (int u = 0; u < 16; ++u) {
        int e = t + u * 512;
        int o = e >> 6, c = e & 63;
        float v = W2[e];
        int dst = c * 68 + ((o >> 3) << 2) + (o & 3);
        if (o & 4) w2b[dst] = v; else w2a[dst] = v;
    }
    if (t < 320) w1s[t] = W1[t];
    if (t < 64)  b1s[t] = b1[t];
    if (t < 128) b2s[t] = b2[t];
    __syncthreads();   // the only barrier

    // ---- h2 lane tile: o in [ow*8, +8), p in [pq*16 + ph*4, +4)
    const int ow = l & 15;
    const int ph = l >> 4;

    float bb[8];
    #pragma unroll
    for (int k = 0; k < 8; ++k) bb[k] = b2s[ow * 8 + k];

    unsigned long long rbest[8];
    #pragma unroll
    for (int k = 0; k < 8; ++k) rbest[k] = 0ull;

    #pragma unroll
    for (int pq = 0; pq < 2; ++pq) {
        // ---- h1 half: c in [0,64), pp in [0,16)  (wave-private, in-order DS)
        #pragma unroll
        for (int u = 0; u < 16; ++u) {
            int e = u * 64 + l;            // 0..1023
            int o1 = e >> 4, pp = e & 15;
            float acc = b1s[o1];
            #pragma unroll
            for (int f = 0; f < 5; ++f)
                acc += w1s[o1 * 5 + f] * flat[a][f * 32 + pq * 16 + pp];
            h1p[a][e] = fmaxf(acc, 0.0f);  // e == o1*16 + pp
        }

        float4 mv4 = *(const float4*)&maskv[a][pq * 16 + ph * 4];
        float mv[4] = {mv4.x, mv4.y, mv4.z, mv4.w};

        float acc[8][4];
        #pragma unroll
        for (int k = 0; k < 8; ++k)
            #pragma unroll
            for (int q = 0; q < 4; ++q) acc[k][q] = 0.0f;

        for (int c4 = 0; c4 < 16; ++c4) {
            float4 wAv[4], wBv[4], hv[4];
            #pragma unroll
            for (int cc = 0; cc < 4; ++cc) {
                int c = c4 * 4 + cc;
                wAv[cc] = *(const float4*)&w2a[c * 68 + ow * 4];
                wBv[cc] = *(const float4*)&w2b[c * 68 + ow * 4];
                hv[cc]  = *(const float4*)&h1p[a][c * 16 + ph * 4];
            }
            #pragma unroll
            for (int cc = 0; cc < 4; ++cc) {
                float wv[8] = {wAv[cc].x, wAv[cc].y, wAv[cc].z, wAv[cc].w,
                               wBv[cc].x, wBv[cc].y, wBv[cc].z, wBv[cc].w};
                float hq[4] = {hv[cc].x, hv[cc].y, hv[cc].z, hv[cc].w};
                #pragma unroll
                for (int k = 0; k < 8; ++k)
                    #pragma unroll
                    for (int q = 0; q < 4; ++q)
                        acc[k][q] += wv[k] * hq[q];   // c ascending: same order as R13
            }
        }

        // ---- bias + relu + mask + partial argmax (running best across halves)
        #pragma unroll
        for (int k = 0; k < 8; ++k) {
            unsigned long long best = rbest[k];
            #pragma unroll
            for (int q = 0; q < 4; ++q) {
                float val = fmaxf(acc[k][q] + bb[k], 0.0f) * mv[q];
                int p = pq * 16 + ph * 4 + q;
                unsigned long long key =
                    ((unsigned long long)__float_as_uint(val) << 32)
                    | (unsigned int)(31 - p);
                if (key > best) best = key;
            }
            rbest[k] = best;
        }
    }

    // ---- cross-lane reduce over ph groups (covers all 32 p) + write feat
    #pragma unroll
    for (int k = 0; k < 8; ++k) {
        unsigned long long best = rbest[k];
        unsigned long long o1 = __shfl_xor(best, 16, 64); if (o1 > best) best = o1;
        unsigned long long o2 = __shfl_xor(best, 32, 64); if (o2 > best) best = o2;
        if (ph == 0) {
            int pbest = 31 - (int)(best & 63ull);
            featb[a][ow * 8 + k] = (float)pbest;
        }
    }

    // ---- dense phase: fully wave-private (z-pool aliases own h1 region,
    //      which this wave is done with). No barrier needed.
    float* z1s = &h1p[a][0];      // 64
    float* z2s = z1s + 64;        // 128
    float* z3s = z1s + 192;       // 64
    float* kvs = z1s + 256;       // 4

    {
        float a0 = bd1[l];
        for (int k = 0; k < 33; ++k) {
            float4 wv = *(const float4*)&Wd1[l * 132 + 4 * k];
            float4 f0 = *(const float4*)&featb[a][4 * k];
            a0 += wv.x * f0.x; a0 += wv.y * f0.y; a0 += wv.z * f0.z; a0 += wv.w * f0.w;
        }
        z1s[l] = fmaxf(a0, 0.0f);
    }

    {
        float accA = bd2[l];
        float accB = bd2[l + 64];
        for (int k = 0; k < 16; ++k) {
            float4 wa = *(const float4*)&Wd2[l * 64 + 4 * k];
            float4 wb = *(const float4*)&Wd2[(l + 64) * 64 + 4 * k];
            float4 f0 = *(const float4*)&z1s[4 * k];
            accA += wa.x * f0.x; accA += wa.y * f0.y;
            accA += wa.z * f0.z; accA += wa.w * f0.w;
            accB += wb.x * f0.x; accB += wb.y * f0.y;
            accB += wb.z * f0.z; accB += wb.w * f0.w;
        }
        z2s[l]      = fmaxf(accA, 0.0f);
        z2s[l + 64] = fmaxf(accB, 0.0f);
    }

    {
        float a0 = bd3[l];
        for (int k = 0; k < 32; ++k) {
            float4 wv = *(const float4*)&Wd3[l * 128 + 4 * k];
            float4 f0 = *(const float4*)&z2s[4 * k];
            a0 += wv.x * f0.x; a0 += wv.y * f0.y; a0 += wv.z * f0.z; a0 += wv.w * f0.w;
        }
        z3s[l] = fmaxf(a0, 0.0f);
    }

    if (l < 4) {
        float acc = bd4[l];
        for (int c = 0; c < 64; ++c) acc += Wd4[l * 64 + c] * z3s[c];
        kvs[l] = 2.0f / (1.0f + expf(-acc)) + 0.2f;
    }
    if (l < 2) {
        float ka = kvs[2 * l + 0];
        float kb = kvs[2 * l + 1];
        float rel = featb[a][128 + l];
        float vel = featb[a][130 + l];
        out[i * 2 + l] = -(ka * rel + kb * vel);
    }
}

extern "C" void kernel_launch(void* const* d_in, const int* in_sizes, int n_in,
                              void* d_out, int out_size, void* d_ws, size_t ws_size,
                              hipStream_t stream)
{
    const float* states = (const float*)d_in[0];
    const float* goals  = (const float*)d_in[1];
    const float* W1  = (const float*)d_in[2];
    const float* b1  = (const float*)d_in[3];
    const float* W2  = (const float*)d_in[4];
    const float* b2  = (const float*)d_in[5];
    const float* Wd1 = (const float*)d_in[6];
    const float* bd1 = (const float*)d_in[7];
    const float* Wd2 = (const float*)d_in[8];
    const float* bd2 = (const float*)d_in[9];
    const float* Wd3 = (const float*)d_in[10];
    const float* bd3 = (const float*)d_in[11];
    const float* Wd4 = (const float*)d_in[12];
    const float* bd4 = (const float*)d_in[13];

    int*   idx = (int*)d_ws;   // 512 KB
    float* out = (float*)d_out;

    topk_kernel<<<NAGENT, 256, 0, stream>>>(states, idx);
    fused_kernel<<<NAGENT / FAGB, 512, 0, stream>>>(states, goals, W1, b1, W2, b2,
                                                    Wd1, bd1, Wd2, bd2, Wd3, bd3,
                                                    Wd4, bd4, idx, out);
}